// Round 1
// baseline (2627.299 us; speedup 1.0000x reference)
//
#include <hip/hip_runtime.h>
#include <math.h>

// Problem constants (from reference setup_inputs)
#define N_ROWS 8192     // N_USER == N_ITEM
#define D 32            // embedding dim (q == k)
#define KNB 4           // neighbors K
#define DV 256          // IN_DIM = K*(D+D)
#define OUT_DIM 64
#define SCALE 0.17677669529663687f  // 1/sqrt(32)

#define BQ 32           // query rows per block
#define BK 32           // key rows per tile

// ---------------------------------------------------------------------------
// Gather: dst[n][k*64 + 0..31] = srcA[adjA[n,k]], dst[n][k*64+32..63] = srcB[adjB[n,k]]
// One thread per float4 of dst. tid = n*64 + f4.
// ---------------------------------------------------------------------------
__global__ void gather_cat_kernel(const float* __restrict__ srcA,
                                  const float* __restrict__ srcB,
                                  const int* __restrict__ adjA,
                                  const int* __restrict__ adjB,
                                  float* __restrict__ dst) {
    int tid = blockIdx.x * blockDim.x + threadIdx.x;
    int n   = tid >> 6;        // row
    int f   = tid & 63;        // float4 index within 256-float row
    int k   = f >> 4;          // neighbor slot 0..3
    int sub = f & 15;          // float4 within 64-float group
    const float* src;
    if (sub < 8) {
        int row = adjA[n * KNB + k];
        src = srcA + (size_t)row * D + sub * 4;
    } else {
        int row = adjB[n * KNB + k];
        src = srcB + (size_t)row * D + (sub - 8) * 4;
    }
    float4 val = *(const float4*)src;
    ((float4*)dst)[tid] = val;
}

// ---------------------------------------------------------------------------
// Flash-style fused self-attention: A = softmax(Q Q^T / sqrt(D)) @ V
// Q: [N_ROWS, 32], V: [N_ROWS, 256], A: [N_ROWS, 256]
// Block: 256 threads, BQ=32 query rows. blockIdx.y selects user/item side.
//
// S-phase mapping: thread t -> query row si = t>>3, key lane sj = t&7,
//   keys j = j0 + sj + 8*jj (jj=0..3). Row's 8 lanes are wave-contiguous ->
//   shfl_xor(1,2,4) reduces max/sum.
// PV-phase mapping: thread t -> cols (t&63)*4 .. +3, rows g*8+ii (g = wave id).
//   P broadcast from LDS as b128 (16 FMA per LDS read -> VALU-bound).
// ---------------------------------------------------------------------------
__global__ __launch_bounds__(256) void flash_kernel(
        const float* __restrict__ Qu, const float* __restrict__ Qi,
        const float* __restrict__ Vu, const float* __restrict__ Vi,
        float* __restrict__ Au, float* __restrict__ Ai) {
    const int side = blockIdx.y;
    const float* __restrict__ Q = side ? Qi : Qu;
    const float* __restrict__ V = side ? Vi : Vu;
    float* __restrict__ A       = side ? Ai : Au;

    const int t   = threadIdx.x;
    const int i0  = blockIdx.x * BQ;
    const int si  = t >> 3;          // S-phase query row 0..31
    const int sj  = t & 7;           // S-phase key lane 0..7
    const int col = (t & 63) << 2;   // PV-phase column base
    const int g   = t >> 6;          // wave id 0..3

    __shared__ __align__(16) float P[BQ][BK + 4];  // stride 36: 16B-aligned rows, 2-way max aliasing
    __shared__ float mrow[BQ], lrow[BQ], arow[BQ];

    // q row in registers (32 floats)
    float4 qr[8];
    {
        const float4* qp = (const float4*)(Q + (size_t)(i0 + si) * D);
#pragma unroll
        for (int d = 0; d < 8; ++d) qr[d] = qp[d];
    }

    float4 o[8];
#pragma unroll
    for (int ii = 0; ii < 8; ++ii) o[ii] = make_float4(0.f, 0.f, 0.f, 0.f);

    if (t < BQ) { mrow[t] = -INFINITY; lrow[t] = 0.f; }
    __syncthreads();

    for (int j0 = 0; j0 < N_ROWS; j0 += BK) {
        // ---- scores for my 4 keys ----
        float s[4];
#pragma unroll
        for (int jj = 0; jj < 4; ++jj) {
            const float4* kp = (const float4*)(Q + (size_t)(j0 + sj + 8 * jj) * D);
            float acc = 0.f;
#pragma unroll
            for (int d = 0; d < 8; ++d) {
                float4 kv = kp[d];
                acc = fmaf(qr[d].x, kv.x, acc);
                acc = fmaf(qr[d].y, kv.y, acc);
                acc = fmaf(qr[d].z, kv.z, acc);
                acc = fmaf(qr[d].w, kv.w, acc);
            }
            s[jj] = acc * SCALE;  // +1.0 bias is softmax-invariant, dropped
        }
        // ---- online softmax (per row over 8 lanes) ----
        float tm = fmaxf(fmaxf(s[0], s[1]), fmaxf(s[2], s[3]));
        tm = fmaxf(tm, __shfl_xor(tm, 1));
        tm = fmaxf(tm, __shfl_xor(tm, 2));
        tm = fmaxf(tm, __shfl_xor(tm, 4));
        float mold = mrow[si];              // read (lockstep) before lane-0 write below
        float mnew = fmaxf(mold, tm);
        float p[4], ps = 0.f;
#pragma unroll
        for (int jj = 0; jj < 4; ++jj) { p[jj] = __expf(s[jj] - mnew); ps += p[jj]; }
        ps += __shfl_xor(ps, 1);
        ps += __shfl_xor(ps, 2);
        ps += __shfl_xor(ps, 4);
        if (sj == 0) {
            float alpha = __expf(mold - mnew);   // first tile: exp(-inf)=0
            mrow[si] = mnew;
            lrow[si] = lrow[si] * alpha + ps;
            arow[si] = alpha;
        }
#pragma unroll
        for (int jj = 0; jj < 4; ++jj) P[si][sj + 8 * jj] = p[jj];
        __syncthreads();

        // ---- rescale accumulators, then O += P @ V-tile ----
#pragma unroll
        for (int ii = 0; ii < 8; ++ii) {
            float a = arow[g * 8 + ii];
            o[ii].x *= a; o[ii].y *= a; o[ii].z *= a; o[ii].w *= a;
        }
        for (int jc = 0; jc < BK; jc += 4) {
            const float* vb = V + (size_t)(j0 + jc) * DV + col;
            float4 v0 = *(const float4*)(vb);
            float4 v1 = *(const float4*)(vb + DV);
            float4 v2 = *(const float4*)(vb + 2 * DV);
            float4 v3 = *(const float4*)(vb + 3 * DV);
#pragma unroll
            for (int ii = 0; ii < 8; ++ii) {
                float4 p4 = *(const float4*)&P[g * 8 + ii][jc];
                o[ii].x = fmaf(p4.x, v0.x, o[ii].x);
                o[ii].y = fmaf(p4.x, v0.y, o[ii].y);
                o[ii].z = fmaf(p4.x, v0.z, o[ii].z);
                o[ii].w = fmaf(p4.x, v0.w, o[ii].w);
                o[ii].x = fmaf(p4.y, v1.x, o[ii].x);
                o[ii].y = fmaf(p4.y, v1.y, o[ii].y);
                o[ii].z = fmaf(p4.y, v1.z, o[ii].z);
                o[ii].w = fmaf(p4.y, v1.w, o[ii].w);
                o[ii].x = fmaf(p4.z, v2.x, o[ii].x);
                o[ii].y = fmaf(p4.z, v2.y, o[ii].y);
                o[ii].z = fmaf(p4.z, v2.z, o[ii].z);
                o[ii].w = fmaf(p4.z, v2.w, o[ii].w);
                o[ii].x = fmaf(p4.w, v3.x, o[ii].x);
                o[ii].y = fmaf(p4.w, v3.y, o[ii].y);
                o[ii].z = fmaf(p4.w, v3.z, o[ii].z);
                o[ii].w = fmaf(p4.w, v3.w, o[ii].w);
            }
        }
        __syncthreads();
    }

    // ---- epilogue: divide by l, store agg ----
#pragma unroll
    for (int ii = 0; ii < 8; ++ii) {
        int r = g * 8 + ii;
        float inv = 1.0f / lrow[r];
        float4 res = make_float4(o[ii].x * inv, o[ii].y * inv, o[ii].z * inv, o[ii].w * inv);
        *(float4*)(A + (size_t)(i0 + r) * DV + col) = res;
    }
}

// ---------------------------------------------------------------------------
// Projection + ReLU: out[n,o] = relu(sum_c agg[n,c] * W[c,o]); user then item.
// ---------------------------------------------------------------------------
__global__ void proj_kernel(const float* __restrict__ Au, const float* __restrict__ Ai,
                            const float* __restrict__ Wu, const float* __restrict__ Wi,
                            float* __restrict__ out) {
    int tid  = blockIdx.x * blockDim.x + threadIdx.x;
    int side = (tid >= N_ROWS * OUT_DIM) ? 1 : 0;
    int idx  = tid - side * N_ROWS * OUT_DIM;
    int n    = idx >> 6;
    int oc   = idx & 63;
    const float* Ag = side ? Ai : Au;
    const float* W  = side ? Wi : Wu;
    const float* ar = Ag + (size_t)n * DV;
    float acc = 0.f;
#pragma unroll 8
    for (int c = 0; c < DV; ++c) acc = fmaf(ar[c], W[c * OUT_DIM + oc], acc);
    out[tid] = fmaxf(acc, 0.f);
}

// ---------------------------------------------------------------------------
extern "C" void kernel_launch(void* const* d_in, const int* in_sizes, int n_in,
                              void* d_out, int out_size, void* d_ws, size_t ws_size,
                              hipStream_t stream) {
    const float* review = (const float*)d_in[0];   // [16384, 32]
    const float* user   = (const float*)d_in[1];   // [8192, 32]
    const float* item   = (const float*)d_in[2];   // [8192, 32]
    const int* adj_ur   = (const int*)d_in[3];     // [8192, 4]
    const int* adj_ri   = (const int*)d_in[4];
    const int* adj_ir   = (const int*)d_in[5];
    const int* adj_ru   = (const int*)d_in[6];
    const float* Wu     = (const float*)d_in[7];   // [256, 64]
    const float* Wi     = (const float*)d_in[8];
    float* out = (float*)d_out;

    // workspace: cat_u, cat_i, agg_u, agg_i  (4 x 8MB = 32 MB)
    float* cat_u = (float*)d_ws;
    float* cat_i = cat_u + (size_t)N_ROWS * DV;
    float* agg_u = cat_i + (size_t)N_ROWS * DV;
    float* agg_i = agg_u + (size_t)N_ROWS * DV;

    // 1) gather neighbor features
    int gthreads = N_ROWS * 64;  // one float4 per thread
    gather_cat_kernel<<<gthreads / 256, 256, 0, stream>>>(review, item, adj_ur, adj_ri, cat_u);
    gather_cat_kernel<<<gthreads / 256, 256, 0, stream>>>(review, user, adj_ir, adj_ru, cat_i);

    // 2) fused attention, both sides in one launch (512 blocks -> 2/CU)
    dim3 fgrid(N_ROWS / BQ, 2);
    flash_kernel<<<fgrid, 256, 0, stream>>>(user, item, cat_u, cat_i, agg_u, agg_i);

    // 3) projection + relu -> d_out (user block then item block)
    proj_kernel<<<(2 * N_ROWS * OUT_DIM) / 256, 256, 0, stream>>>(agg_u, agg_i, Wu, Wi, out);
}

// Round 2
// 754.024 us; speedup vs baseline: 3.4844x; 3.4844x over previous
//
#include <hip/hip_runtime.h>
#include <math.h>

// Problem constants
#define NR 8192        // N_USER == N_ITEM
#define DQ 32          // embedding dim
#define DV 256         // IN_DIM = K*(D+D)
#define OUT_DIM 64
#define NSPLIT 2
#define KEYS_PER_SPLIT (NR / NSPLIT)   // 4096
#define BK 64          // keys per inner iteration
#define QSCALE 0.42044820762685725f    // 2^-1.25; applied to both Q copies -> net 1/sqrt(32)

typedef short short8 __attribute__((ext_vector_type(8)));   // 8 bf16 (4 VGPRs)
typedef float f32x16 __attribute__((ext_vector_type(16)));  // 32x32 MFMA acc

__device__ __forceinline__ unsigned short f32_to_bf16(float f) {
    union { float f; unsigned int u; } v; v.f = f;
    unsigned int u = v.u + 0x7FFFu + ((v.u >> 16) & 1u);    // RNE
    return (unsigned short)(u >> 16);
}
__device__ __forceinline__ float bf16_to_f32(unsigned short h) {
    union { unsigned int u; float f; } v; v.u = ((unsigned int)h) << 16;
    return v.f;
}

// ---------------------------------------------------------------------------
// Convert user/item vecs to bf16, pre-scaled by 2^-1.25 (so S = q.q/sqrt(32)).
// ---------------------------------------------------------------------------
__global__ void qconv_kernel(const float* __restrict__ user,
                             const float* __restrict__ item,
                             unsigned short* __restrict__ qh) {
    int side = blockIdx.y;
    int i = blockIdx.x * blockDim.x + threadIdx.x;   // 0 .. NR*DQ-1
    const float* src = side ? item : user;
    qh[(size_t)side * NR * DQ + i] = f32_to_bf16(src[i] * QSCALE);
}

// ---------------------------------------------------------------------------
// Gather neighbor features into k-tiled V^T bf16 layout:
//   vt[side][ (key>>4)*4096 + c*16 + (key&15) ] = cat[key][c]
// where cat[key][c]: c = knb*64 + s; s<32 -> srcA[adjA[key][knb]][s]
//                                     else -> srcB[adjB[key][knb]][s-32]
// Writes are perfectly coalesced (el == flat dst index); reads are scattered
// 4B from L2-resident source tables.
// ---------------------------------------------------------------------------
__global__ void gather_vt_kernel(const float* __restrict__ review,
                                 const float* __restrict__ user,
                                 const float* __restrict__ item,
                                 const int* __restrict__ adj_ur, const int* __restrict__ adj_ri,
                                 const int* __restrict__ adj_ir, const int* __restrict__ adj_ru,
                                 unsigned short* __restrict__ vt) {
    int side = blockIdx.y;
    int el = blockIdx.x * blockDim.x + threadIdx.x;  // 0 .. NR*DV-1
    int kt  = el >> 12;        // key tile (16 keys x 256 c = 4096 elems)
    int c   = (el >> 4) & 255;
    int klo = el & 15;
    int key = kt * 16 + klo;
    int knb = c >> 6;
    int s   = c & 63;
    const int* adjA = side ? adj_ir : adj_ur;
    const int* adjB = side ? adj_ru : adj_ri;
    const float* srcB = side ? user : item;
    float val;
    if (s < 32) val = review[(size_t)adjA[key * 4 + knb] * DQ + s];
    else        val = srcB[(size_t)adjB[key * 4 + knb] * DQ + (s - 32)];
    vt[(size_t)side * NR * DV + el] = f32_to_bf16(val);
}

// ---------------------------------------------------------------------------
// Wave-independent MFMA flash attention with split-K (no barriers).
// One wave = 32 q-rows x one key-split (4096 keys). 256 blocks x 4 waves.
// Partials: opart = sum(p*V) (bf16), lpart = sum(p) (fp32); merged later.
// Layouts (mfma_f32_32x32x16_bf16, verified m74/m101):
//   A: lane holds A[m=lane&31][k=(lane>>5)*8+i]
//   B: lane holds B[k=(lane>>5)*8+i][n=lane&31]
//   C: col=lane&31, row=(reg&3)+8*(reg>>2)+4*(lane>>5)
// ---------------------------------------------------------------------------
__global__ __launch_bounds__(256, 1) void flash_kernel(
        const unsigned short* __restrict__ qh,   // [2][NR*32] bf16, pre-scaled
        const unsigned short* __restrict__ vt,   // [2][NR*256] bf16, k-tiled
        unsigned short* __restrict__ opart,      // [2][NSPLIT][NR][256] bf16
        float* __restrict__ lpart)               // [2][NSPLIT][NR]
{
    const int bx   = blockIdx.x;
    const int side = bx & 1;              // sides on alternating XCDs (bx%8 heuristic)
    const int sp   = (bx >> 1) & 1;
    const int rg   = bx >> 2;             // 0..63: 128-row group
    const int w    = threadIdx.x >> 6;
    const int lane = threadIdx.x & 63;
    const int ln   = lane & 31;
    const int h    = lane >> 5;

    const int m0 = rg * 128 + w * 32;
    const unsigned short* Q  = qh + (size_t)side * NR * DQ;
    const unsigned short* VT = vt + (size_t)side * NR * DV;

    // wave-private P staging: stride 72 -> conflict-free b16 writes, 16B rows
    __shared__ unsigned short Plds[4][32][72];
    unsigned short (*P)[72] = Plds[w];

    // persistent Q A-fragments (rows m0..m0+31, k split in two halves)
    short8 aq0 = *(const short8*)(Q + (size_t)(m0 + ln) * DQ + h * 8);
    short8 aq1 = *(const short8*)(Q + (size_t)(m0 + ln) * DQ + 16 + h * 8);

    f32x16 zf;
#pragma unroll
    for (int r = 0; r < 16; ++r) zf[r] = 0.f;
    f32x16 o[8];
#pragma unroll
    for (int t = 0; t < 8; ++t) o[t] = zf;
    float l_acc[16];
#pragma unroll
    for (int r = 0; r < 16; ++r) l_acc[r] = 0.f;

    const int k_begin = sp * KEYS_PER_SPLIT;
    for (int it = 0; it < KEYS_PER_SPLIT / BK; ++it) {
        const int j0 = k_begin + it * BK;

        // ---- S = Q K^T (two 32x32 tiles over 64 keys) ----
        const unsigned short* kb = Q + (size_t)(j0 + ln) * DQ + h * 8;
        short8 bq00 = *(const short8*)(kb);
        short8 bq01 = *(const short8*)(kb + 16);
        short8 bq10 = *(const short8*)(kb + (size_t)32 * DQ);
        short8 bq11 = *(const short8*)(kb + (size_t)32 * DQ + 16);
        f32x16 s0 = __builtin_amdgcn_mfma_f32_32x32x16_bf16(aq0, bq00, zf, 0, 0, 0);
        s0 = __builtin_amdgcn_mfma_f32_32x32x16_bf16(aq1, bq01, s0, 0, 0, 0);
        f32x16 s1 = __builtin_amdgcn_mfma_f32_32x32x16_bf16(aq0, bq10, zf, 0, 0, 0);
        s1 = __builtin_amdgcn_mfma_f32_32x32x16_bf16(aq1, bq11, s1, 0, 0, 0);

        // ---- p = exp(s)  (no max tracking: s bounded ~18, fp32 exp safe) ----
        float p0[16], p1[16];
#pragma unroll
        for (int r = 0; r < 16; ++r) { p0[r] = __expf(s0[r]); p1[r] = __expf(s1[r]); }

        // ---- l += row sums (rows live across the 32 lanes of each half) ----
#pragma unroll
        for (int r = 0; r < 16; ++r) {
            float ps = p0[r] + p1[r];
            ps += __shfl_xor(ps, 1);
            ps += __shfl_xor(ps, 2);
            ps += __shfl_xor(ps, 4);
            ps += __shfl_xor(ps, 8);
            ps += __shfl_xor(ps, 16);
            l_acc[r] += ps;
        }

        // ---- P -> LDS (C layout -> row-major bf16) ----
#pragma unroll
        for (int r = 0; r < 16; ++r) {
            int row = (r & 3) + ((r >> 2) << 3) + h * 4;
            P[row][ln]      = f32_to_bf16(p0[r]);
            P[row][32 + ln] = f32_to_bf16(p1[r]);
        }

        // ---- O += P @ V-tile (A from wave-private LDS, B coalesced global) ----
#pragma unroll
        for (int ks = 0; ks < 4; ++ks) {
            short8 ap = *(const short8*)&P[ln][ks * 16 + h * 8];
            const unsigned short* vb = VT + ((size_t)(j0 >> 4) + ks) * (DV * 16) + h * 8;
#pragma unroll
            for (int ct = 0; ct < 8; ++ct) {
                short8 bv = *(const short8*)(vb + (size_t)(ct * 32 + ln) * 16);
                o[ct] = __builtin_amdgcn_mfma_f32_32x32x16_bf16(ap, bv, o[ct], 0, 0, 0);
            }
        }
    }

    // ---- store raw partials ----
    unsigned short* op = opart + (((size_t)(side * NSPLIT + sp)) * NR + m0) * DV;
#pragma unroll
    for (int r = 0; r < 16; ++r) {
        int row = (r & 3) + ((r >> 2) << 3) + h * 4;
#pragma unroll
        for (int ct = 0; ct < 8; ++ct)
            op[(size_t)row * DV + ct * 32 + ln] = f32_to_bf16(o[ct][r]);
    }
    if (ln == 0) {
#pragma unroll
        for (int r = 0; r < 16; ++r) {
            int row = (r & 3) + ((r >> 2) << 3) + h * 4;
            lpart[(size_t)(side * NSPLIT + sp) * NR + m0 + row] = l_acc[r];
        }
    }
}

// ---------------------------------------------------------------------------
// Merge split-K partials + projection + ReLU, fused.
// out[side][n][o] = relu( (sum_c (Op0+Op1)[n][c] * W[c][o]) / (L0+L1) )
// ---------------------------------------------------------------------------
__global__ void merge_proj_kernel(const unsigned short* __restrict__ opart,
                                  const float* __restrict__ lpart,
                                  const float* __restrict__ Wu,
                                  const float* __restrict__ Wi,
                                  float* __restrict__ out) {
    int tid  = blockIdx.x * blockDim.x + threadIdx.x;
    int side = (tid >= NR * OUT_DIM) ? 1 : 0;
    int idx  = tid - side * NR * OUT_DIM;
    int n    = idx >> 6;
    int oc   = idx & 63;
    const float* W = side ? Wi : Wu;
    const unsigned short* o0 = opart + ((size_t)(side * NSPLIT + 0) * NR + n) * DV;
    const unsigned short* o1 = opart + ((size_t)(side * NSPLIT + 1) * NR + n) * DV;
    float L = lpart[(size_t)(side * NSPLIT + 0) * NR + n]
            + lpart[(size_t)(side * NSPLIT + 1) * NR + n];
    float inv = 1.0f / L;
    float acc = 0.f;
#pragma unroll 4
    for (int c = 0; c < DV; ++c) {
        float a = bf16_to_f32(o0[c]) + bf16_to_f32(o1[c]);
        acc = fmaf(a, W[c * OUT_DIM + oc], acc);
    }
    out[tid] = fmaxf(acc * inv, 0.f);
}

// ---------------------------------------------------------------------------
extern "C" void kernel_launch(void* const* d_in, const int* in_sizes, int n_in,
                              void* d_out, int out_size, void* d_ws, size_t ws_size,
                              hipStream_t stream) {
    const float* review = (const float*)d_in[0];   // [16384, 32]
    const float* user   = (const float*)d_in[1];   // [8192, 32]
    const float* item   = (const float*)d_in[2];   // [8192, 32]
    const int* adj_ur   = (const int*)d_in[3];
    const int* adj_ri   = (const int*)d_in[4];
    const int* adj_ir   = (const int*)d_in[5];
    const int* adj_ru   = (const int*)d_in[6];
    const float* Wu     = (const float*)d_in[7];   // [256, 64]
    const float* Wi     = (const float*)d_in[8];
    float* out = (float*)d_out;

    // workspace layout (25.3 MB total):
    unsigned short* qh    = (unsigned short*)d_ws;            // 1 MB
    unsigned short* vt    = qh + (size_t)2 * NR * DQ;         // 8 MB
    unsigned short* opart = vt + (size_t)2 * NR * DV;         // 16 MB
    float*          lpart = (float*)(opart + (size_t)2 * NSPLIT * NR * DV);  // 128 KB

    qconv_kernel<<<dim3(NR * DQ / 256, 2), 256, 0, stream>>>(user, item, qh);
    gather_vt_kernel<<<dim3(NR * DV / 256, 2), 256, 0, stream>>>(
        review, user, item, adj_ur, adj_ri, adj_ir, adj_ru, vt);
    flash_kernel<<<2 * NSPLIT * (NR / 128), 256, 0, stream>>>(qh, vt, opart, lpart);
    merge_proj_kernel<<<2 * NR * OUT_DIM / 256, 256, 0, stream>>>(opart, lpart, Wu, Wi, out);
}

// Round 3
// 306.352 us; speedup vs baseline: 8.5761x; 2.4613x over previous
//
#include <hip/hip_runtime.h>
#include <math.h>

// ---------------------------------------------------------------------------
// AttentionAggregator: two self-attentions (N=8192, D=32, Dv=256) + 256->64
// projection. Round-3 design:
//  - MFMA flash attention, wave-independent K-loop (no barriers).
//  - wave tile = 64 q-rows x 128 V-cols (col-split per block) -> 2x B reuse.
//  - V in "frag-native" bf16 layout: every B-frag load = contiguous 1KB/wave.
//  - (side,colhalf) == bx&3 -> XCD-affine (bx%8): each XCD's L2 holds 2.5MB.
//  - l (softmax denom) via ones-MFMA on the same bf16 P frags as O.
//  - projection fused in epilogue (MFMA vs bf16 W), atomicAdd fp32 partials.
// ---------------------------------------------------------------------------
#define NR 8192
#define DQ 32
#define DV 256
#define OUT_DIM 64
#define NSPLIT 4
#define BK 64
// 2^-1.25 * sqrt(log2(e)): qh = q*QS2 -> dot = (q.q')/sqrt(32)*log2(e); p = 2^s
#define QSCALE2 0.5050114839784955f

typedef short short8 __attribute__((ext_vector_type(8)));   // 8 bf16
typedef float f32x16 __attribute__((ext_vector_type(16)));  // 32x32 MFMA acc

__device__ __forceinline__ unsigned short f32_to_bf16(float f) {
    union { float f; unsigned int u; } v; v.f = f;
    unsigned int u = v.u + 0x7FFFu + ((v.u >> 16) & 1u);    // RNE
    return (unsigned short)(u >> 16);
}
__device__ __forceinline__ float exp2_fast(float x) {
#if __has_builtin(__builtin_amdgcn_exp2f)
    return __builtin_amdgcn_exp2f(x);
#else
    return __expf(x * 0.6931471805599453f);   // e^(x ln2) = 2^x
#endif
}

// ---------------------------------------------------------------------------
// Zero the atomic accumulators (acc 4MB + lsum 64KB), float4 per thread.
// ---------------------------------------------------------------------------
__global__ void zero_kernel(float4* __restrict__ p) {
    p[blockIdx.x * blockDim.x + threadIdx.x] = make_float4(0.f, 0.f, 0.f, 0.f);
}

// ---------------------------------------------------------------------------
// Q -> bf16, scaled into log2-softmax domain.
// ---------------------------------------------------------------------------
__global__ void qconv_kernel(const float* __restrict__ user,
                             const float* __restrict__ item,
                             unsigned short* __restrict__ qh) {
    int side = blockIdx.y;
    int i = blockIdx.x * blockDim.x + threadIdx.x;
    const float* src = side ? item : user;
    qh[(size_t)side * NR * DQ + i] = f32_to_bf16(src[i] * QSCALE2);
}

// ---------------------------------------------------------------------------
// W -> bf16 B-frag-native: wbf[wm][ch][kt][nt][lane64][8] holds
//   W[ch*128 + kt*16 + (lane>>5)*8 + i][nt*32 + (lane&31)].  4096 threads.
// ---------------------------------------------------------------------------
__global__ void wconv_kernel(const float* __restrict__ Wu,
                             const float* __restrict__ Wi,
                             unsigned short* __restrict__ wbf) {
    int g  = blockIdx.x * blockDim.x + threadIdx.x;   // 0..4095
    int ln = g & 31, h = (g >> 5) & 1, nt = (g >> 6) & 1;
    int kt = (g >> 7) & 7, ch = (g >> 10) & 1, wm = g >> 11;
    const float* W = wm ? Wi : Wu;
    unsigned short* dst = wbf + (size_t)g * 8;
#pragma unroll
    for (int i = 0; i < 8; ++i) {
        int k = ch * 128 + kt * 16 + h * 8 + i;
        dst[i] = f32_to_bf16(W[k * OUT_DIM + nt * 32 + ln]);
    }
}

// ---------------------------------------------------------------------------
// Gather neighbors into frag-native vt:
//   vt[side][ch][kt 512][ct' 4][h 2][ln 32][i 8] = V[kt*16+h*8+i][ch*128+ct'*32+ln]
// One thread per 8-key group (16B write); 8 scattered 4B reads each.
// ---------------------------------------------------------------------------
__global__ void gather_vt_kernel(const float* __restrict__ review,
                                 const float* __restrict__ user,
                                 const float* __restrict__ item,
                                 const int* __restrict__ adj_ur, const int* __restrict__ adj_ri,
                                 const int* __restrict__ adj_ir, const int* __restrict__ adj_ru,
                                 unsigned short* __restrict__ vt) {
    int side = blockIdx.y;
    int g  = blockIdx.x * blockDim.x + threadIdx.x;   // 0..262143 per side
    int ln = g & 31, h = (g >> 5) & 1, ct = (g >> 6) & 3;
    int kt = (g >> 8) & 511, ch = g >> 17;
    int n   = ch * 128 + ct * 32 + ln;   // 0..255
    int knb = n >> 6;                    // neighbor slot
    int s   = n & 63;                    // dim within concat pair
    const int* adjA   = side ? adj_ir : adj_ur;
    const int* adjB   = side ? adj_ru : adj_ri;
    const float* srcB = side ? user : item;
    short8 out;
#pragma unroll
    for (int i = 0; i < 8; ++i) {
        int key = kt * 16 + h * 8 + i;
        float val;
        if (s < 32) val = review[(size_t)adjA[key * 4 + knb] * DQ + s];
        else        val = srcB[(size_t)adjB[key * 4 + knb] * DQ + (s - 32)];
        out[i] = (short)f32_to_bf16(val);
    }
    *(short8*)(vt + (size_t)side * 2 * NR * 128 + (size_t)g * 8) = out;
}

// ---------------------------------------------------------------------------
// MFMA flash attention + fused projection. Grid 512 blocks x 256 threads.
// bx: side=bx&1, ch=(bx>>1)&1, sp=(bx>>2)&3 (key split), rb=bx>>4 (row grp).
// Wave tile: 64 rows x 128 cols; acc o[2][4] f32x16 (128 VGPR); l via
// ones-MFMA. P round-trips through wave-private LDS (measured conflict-free
// 72-short stride in R2). Epilogue: O->bf16->LDS, O@Wslice MFMA, atomicAdd.
// ---------------------------------------------------------------------------
__global__ __launch_bounds__(256, 2) void flash_kernel(
        const unsigned short* __restrict__ qh,
        const unsigned short* __restrict__ vt,
        const unsigned short* __restrict__ wbf,
        float* __restrict__ acc,     // [2][NR][64]
        float* __restrict__ lsum)    // [2][NR]
{
    const int bx   = blockIdx.x;
    const int side = bx & 1;
    const int ch   = (bx >> 1) & 1;
    const int sp   = (bx >> 2) & (NSPLIT - 1);
    const int rb   = bx >> 4;                  // 0..31
    const int w    = threadIdx.x >> 6;
    const int lane = threadIdx.x & 63;
    const int ln   = lane & 31;
    const int h    = lane >> 5;

    const int m0 = rb * 256 + w * 64;          // wave's first row
    const unsigned short* Q  = qh + (size_t)side * NR * DQ;
    const unsigned short* VT = vt + ((size_t)(side * 2 + ch)) * NR * 128;

    // wave-private scratch: P phase uses stride 72 (64x72), epilogue 64x136
    __shared__ __align__(16) unsigned short Sbuf[4][64 * 136];
    unsigned short* Pw = Sbuf[w];

    // persistent Q A-frags: 2 m-tiles x 2 dim-halves
    short8 aq[2][2];
#pragma unroll
    for (int mt = 0; mt < 2; ++mt)
#pragma unroll
        for (int dh = 0; dh < 2; ++dh)
            aq[mt][dh] = *(const short8*)(Q + (size_t)(m0 + mt * 32 + ln) * DQ + dh * 16 + h * 8);

    const unsigned short one_bf = 0x3F80;
    short8 bones;
#pragma unroll
    for (int i = 0; i < 8; ++i) bones[i] = (short)one_bf;

    f32x16 zf;
#pragma unroll
    for (int r = 0; r < 16; ++r) zf[r] = 0.f;
    f32x16 o[2][4];
#pragma unroll
    for (int mt = 0; mt < 2; ++mt)
#pragma unroll
        for (int ct = 0; ct < 4; ++ct) o[mt][ct] = zf;
    f32x16 l0 = zf, l1 = zf;

    const int j_begin = sp * (NR / NSPLIT);
    for (int it = 0; it < (NR / NSPLIT) / BK; ++it) {
        const int j0  = j_begin + it * BK;
        const int kt0 = j0 >> 4;

        // ---- S = Q K^T -> p = 2^s -> P (bf16) into LDS, per 32-key tile ----
#pragma unroll
        for (int kt = 0; kt < 2; ++kt) {
            const unsigned short* kb = Q + (size_t)(j0 + kt * 32 + ln) * DQ + h * 8;
            short8 bq0 = *(const short8*)(kb);
            short8 bq1 = *(const short8*)(kb + 16);
            f32x16 s0 = __builtin_amdgcn_mfma_f32_32x32x16_bf16(aq[0][0], bq0, zf, 0, 0, 0);
            s0 = __builtin_amdgcn_mfma_f32_32x32x16_bf16(aq[0][1], bq1, s0, 0, 0, 0);
            f32x16 s1 = __builtin_amdgcn_mfma_f32_32x32x16_bf16(aq[1][0], bq0, zf, 0, 0, 0);
            s1 = __builtin_amdgcn_mfma_f32_32x32x16_bf16(aq[1][1], bq1, s1, 0, 0, 0);
#pragma unroll
            for (int r = 0; r < 16; ++r) {
                int row = (r & 3) + ((r >> 2) << 3) + h * 4;
                Pw[row * 72 + kt * 32 + ln]        = f32_to_bf16(exp2_fast(s0[r]));
                Pw[(32 + row) * 72 + kt * 32 + ln] = f32_to_bf16(exp2_fast(s1[r]));
            }
        }

        // ---- O += P @ V ; l += P @ ones  (all frags wave-private) ----
#pragma unroll
        for (int ks = 0; ks < 4; ++ks) {
            short8 ap0 = *(const short8*)(Pw + ln * 72 + ks * 16 + h * 8);
            short8 ap1 = *(const short8*)(Pw + (32 + ln) * 72 + ks * 16 + h * 8);
            l0 = __builtin_amdgcn_mfma_f32_32x32x16_bf16(ap0, bones, l0, 0, 0, 0);
            l1 = __builtin_amdgcn_mfma_f32_32x32x16_bf16(ap1, bones, l1, 0, 0, 0);
            const unsigned short* vb = VT + (size_t)(kt0 + ks) * 2048 + (size_t)lane * 8;
#pragma unroll
            for (int ct = 0; ct < 4; ++ct) {
                short8 bv = *(const short8*)(vb + ct * 512);
                o[0][ct] = __builtin_amdgcn_mfma_f32_32x32x16_bf16(ap0, bv, o[0][ct], 0, 0, 0);
                o[1][ct] = __builtin_amdgcn_mfma_f32_32x32x16_bf16(ap1, bv, o[1][ct], 0, 0, 0);
            }
        }
    }

    // ---- epilogue: O -> bf16 A-layout in LDS (stride 136) ----
#pragma unroll
    for (int mt = 0; mt < 2; ++mt)
#pragma unroll
        for (int ct = 0; ct < 4; ++ct)
#pragma unroll
            for (int r = 0; r < 16; ++r) {
                int row = mt * 32 + (r & 3) + ((r >> 2) << 3) + h * 4;
                Pw[row * 136 + ct * 32 + ln] = f32_to_bf16(o[mt][ct][r]);
            }

    // ---- proj: pp = Obf(64x128) @ Wslice(128x64) ----
    f32x16 pp[2][2];
    pp[0][0] = zf; pp[0][1] = zf; pp[1][0] = zf; pp[1][1] = zf;
    const unsigned short* wb_base = wbf + ((size_t)(side * 2 + ch) * 8) * 1024;
#pragma unroll
    for (int kt = 0; kt < 8; ++kt) {
        short8 a0 = *(const short8*)(Pw + ln * 136 + kt * 16 + h * 8);
        short8 a1 = *(const short8*)(Pw + (32 + ln) * 136 + kt * 16 + h * 8);
#pragma unroll
        for (int nt = 0; nt < 2; ++nt) {
            short8 bw = *(const short8*)(wb_base + (size_t)kt * 1024 + nt * 512 + (size_t)lane * 8);
            pp[0][nt] = __builtin_amdgcn_mfma_f32_32x32x16_bf16(a0, bw, pp[0][nt], 0, 0, 0);
            pp[1][nt] = __builtin_amdgcn_mfma_f32_32x32x16_bf16(a1, bw, pp[1][nt], 0, 0, 0);
        }
    }

    // ---- atomic accumulate projected partials + denominators ----
#pragma unroll
    for (int mt = 0; mt < 2; ++mt)
#pragma unroll
        for (int nt = 0; nt < 2; ++nt)
#pragma unroll
            for (int r = 0; r < 16; ++r) {
                int row = (r & 3) + ((r >> 2) << 3) + h * 4;
                int gm  = m0 + mt * 32 + row;
                atomicAdd(&acc[((size_t)side * NR + gm) * OUT_DIM + nt * 32 + ln],
                          pp[mt][nt][r]);
            }
    if (ch == 0 && ln == 0) {
#pragma unroll
        for (int r = 0; r < 16; ++r) {
            int row = (r & 3) + ((r >> 2) << 3) + h * 4;
            atomicAdd(&lsum[(size_t)side * NR + m0 + row], l0[r]);
            atomicAdd(&lsum[(size_t)side * NR + m0 + 32 + row], l1[r]);
        }
    }
}

// ---------------------------------------------------------------------------
// out = relu(acc / lsum)
// ---------------------------------------------------------------------------
__global__ void final_kernel(const float* __restrict__ acc,
                             const float* __restrict__ lsum,
                             float* __restrict__ out) {
    int tid = blockIdx.x * blockDim.x + threadIdx.x;   // 0..2*NR*64-1
    int row = tid >> 6;                                 // [2*NR)
    out[tid] = fmaxf(acc[tid] / lsum[row], 0.f);
}

// ---------------------------------------------------------------------------
extern "C" void kernel_launch(void* const* d_in, const int* in_sizes, int n_in,
                              void* d_out, int out_size, void* d_ws, size_t ws_size,
                              hipStream_t stream) {
    const float* review = (const float*)d_in[0];
    const float* user   = (const float*)d_in[1];
    const float* item   = (const float*)d_in[2];
    const int* adj_ur   = (const int*)d_in[3];
    const int* adj_ri   = (const int*)d_in[4];
    const int* adj_ir   = (const int*)d_in[5];
    const int* adj_ru   = (const int*)d_in[6];
    const float* Wu     = (const float*)d_in[7];
    const float* Wi     = (const float*)d_in[8];
    float* out = (float*)d_out;

    // ws layout (13.3 MB): acc | lsum | vt | qh | wbf
    float* acc  = (float*)d_ws;                              // 2*NR*64   f32
    float* lsum = acc + (size_t)2 * NR * OUT_DIM;            // 2*NR      f32
    unsigned short* vt  = (unsigned short*)(lsum + 2 * NR);  // 2*2*NR*128 bf16
    unsigned short* qh  = vt + (size_t)4 * NR * 128;         // 2*NR*32   bf16
    unsigned short* wbf = qh + (size_t)2 * NR * DQ;          // 32768     bf16

    int zero_f4 = (2 * NR * OUT_DIM + 2 * NR) / 4;           // 266240
    zero_kernel<<<zero_f4 / 256, 256, 0, stream>>>((float4*)acc);
    qconv_kernel<<<dim3(NR * DQ / 256, 2), 256, 0, stream>>>(user, item, qh);
    wconv_kernel<<<16, 256, 0, stream>>>(Wu, Wi, wbf);
    gather_vt_kernel<<<dim3(2 * NR * 128 / 8 / 256, 2), 256, 0, stream>>>(
        review, user, item, adj_ur, adj_ri, adj_ir, adj_ru, vt);
    flash_kernel<<<2 * 2 * NSPLIT * (NR / 256), 256, 0, stream>>>(qh, vt, wbf, acc, lsum);
    final_kernel<<<2 * NR * OUT_DIM / 256, 256, 0, stream>>>(acc, lsum, out);
}